// Round 4
// baseline (6612.714 us; speedup 1.0000x reference)
//
#include <hip/hip_runtime.h>

#define TMAX 8192
#define H 128

__device__ __forceinline__ float sigf(float x)       { return 1.f / (1.f + __expf(-x)); }
__device__ __forceinline__ float tanhf_fast(float x) { return 2.f / (1.f + __expf(-2.f * x)) - 1.f; }

// One block, 512 threads = 8 waves (2/SIMD).
// Thread t: h-element j = t>>2, k-quarter q = t&3; holds all 4 gate rows
// {j, j+128, j+256, j+384} x 32-wide k-slice = 128 weight floats.
//
// ROUND 4 CHANGE: weights are loaded via asm volatile global_load_dwordx4.
// Rounds 1-3 proved the compiler treats these (provably invariant) loads as
// rematerializable and re-issues them INSIDE the step loop (VGPR_Count 84-92
// < the 128-float footprint; ~256 KB/step streamed from L1/L2 = the wall).
// An asm-defined value cannot be rematerialized: the RA must keep it
// register-resident. waves_per_eu(2,2) gives the 256-VGPR budget it needs.
__attribute__((amdgpu_waves_per_eu(2, 2)))
__global__ __launch_bounds__(512)
void lstm_seq_kernel(const float* __restrict__ x,
                     const float* __restrict__ Wih,
                     const float* __restrict__ Whh,
                     const float* __restrict__ bih,
                     const float* __restrict__ bhh,
                     const float* __restrict__ Wlin,
                     const float* __restrict__ blin,
                     const float* __restrict__ h0,
                     const float* __restrict__ c0,
                     float* __restrict__ out,
                     int T)
{
    __shared__ float  x_s[TMAX];      // 32 KB
    __shared__ float4 h_il[H / 4];    // interleaved h: slot i*4+q = h[q*32 + i*4 .. +3]

    const int t = threadIdx.x;        // 0..511
    const int j = t >> 2;             // h element 0..127
    const int q = t & 3;              // k-quarter

    // Stage input sequence (one-time, coalesced).
    for (int idx = t; idx < T; idx += 512) x_s[idx] = x[idx];

    const float4* pi = (const float4*)(Whh + (j      ) * H + q * 32);
    const float4* pf = (const float4*)(Whh + (j + 128) * H + q * 32);
    const float4* pg = (const float4*)(Whh + (j + 256) * H + q * 32);
    const float4* po = (const float4*)(Whh + (j + 384) * H + q * 32);

    // Non-rematerializable weight loads: 32 x global_load_dwordx4 = 128 VGPRs.
#define ASMLD4(dst, base, n) \
    { const float4* _a = (base) + (n); \
      asm volatile("global_load_dwordx4 %0, %1, off" : "=v"(dst) : "v"(_a)); }

    float4 wi0, wi1, wi2, wi3, wi4, wi5, wi6, wi7;
    float4 wf0, wf1, wf2, wf3, wf4, wf5, wf6, wf7;
    float4 wg0, wg1, wg2, wg3, wg4, wg5, wg6, wg7;
    float4 wo0, wo1, wo2, wo3, wo4, wo5, wo6, wo7;
#define LOADW(n) \
    ASMLD4(wi##n, pi, n) ASMLD4(wf##n, pf, n) ASMLD4(wg##n, pg, n) ASMLD4(wo##n, po, n)
    LOADW(0) LOADW(1) LOADW(2) LOADW(3) LOADW(4) LOADW(5) LOADW(6) LOADW(7)
#undef LOADW
#undef ASMLD4

    // x-weights and biases: same treatment (8 scalars).
#define ASMLD1(dst, ptr) \
    { const float* _a = (ptr); \
      asm volatile("global_load_dword %0, %1, off" : "=v"(dst) : "v"(_a)); }
    float wxi, wxf, wxg, wxo, vbi, vbf, vbg, vbo, vb2i, vb2f, vb2g, vb2o;
    ASMLD1(wxi, Wih + j)        ASMLD1(wxf, Wih + j + 128)
    ASMLD1(wxg, Wih + j + 256)  ASMLD1(wxo, Wih + j + 384)
    ASMLD1(vbi, bih + j)        ASMLD1(vbf, bih + j + 128)
    ASMLD1(vbg, bih + j + 256)  ASMLD1(vbo, bih + j + 384)
    ASMLD1(vb2i, bhh + j)       ASMLD1(vb2f, bhh + j + 128)
    ASMLD1(vb2g, bhh + j + 256) ASMLD1(vb2o, bhh + j + 384)
#undef ASMLD1

    asm volatile("s_waitcnt vmcnt(0)");

    // Only quarter 0 contributes x-weight and bias to its partial.
    const bool lead = (q == 0);
    if (!lead) { wxi = 0.f; wxf = 0.f; wxg = 0.f; wxo = 0.f; }
    const float bi_ = lead ? vbi + vb2i : 0.f;
    const float bf_ = lead ? vbf + vb2f : 0.f;
    const float bg_ = lead ? vbg + vb2g : 0.f;
    const float bo_ = lead ? vbo + vb2o : 0.f;

    float c = c0[j];                  // replicated across the 4 lanes of a group

    // h0 -> interleaved LDS.
    if (t < H) {
        const int fi = ((t >> 2) & 7) * 16 + (t >> 5) * 4 + (t & 3);
        ((float*)h_il)[fi] = h0[t];
    }
    // My h-write slot (linear j -> interleaved float index).
    const int widx = ((j >> 2) & 7) * 16 + (j >> 5) * 4 + (j & 3);
    __syncthreads();                  // also a scheduling wall: no use hoists above

    for (int step = 0; step < T; ++step) {
        const float xv = x_s[step];   // broadcast
        float ai0 = fmaf(xv, wxi, bi_), ai1 = 0.f;
        float af0 = fmaf(xv, wxf, bf_), af1 = 0.f;
        float ag0 = fmaf(xv, wxg, bg_), ag1 = 0.f;
        float ao0 = fmaf(xv, wxo, bo_), ao1 = 0.f;

#define DO(n) { \
        const float4 h4 = h_il[n * 4 + q]; \
        ai0 = fmaf(wi##n.x, h4.x, ai0); ai1 = fmaf(wi##n.y, h4.y, ai1); \
        ai0 = fmaf(wi##n.z, h4.z, ai0); ai1 = fmaf(wi##n.w, h4.w, ai1); \
        af0 = fmaf(wf##n.x, h4.x, af0); af1 = fmaf(wf##n.y, h4.y, af1); \
        af0 = fmaf(wf##n.z, h4.z, af0); af1 = fmaf(wf##n.w, h4.w, af1); \
        ag0 = fmaf(wg##n.x, h4.x, ag0); ag1 = fmaf(wg##n.y, h4.y, ag1); \
        ag0 = fmaf(wg##n.z, h4.z, ag0); ag1 = fmaf(wg##n.w, h4.w, ag1); \
        ao0 = fmaf(wo##n.x, h4.x, ao0); ao1 = fmaf(wo##n.y, h4.y, ao1); \
        ao0 = fmaf(wo##n.z, h4.z, ao0); ao1 = fmaf(wo##n.w, h4.w, ao1); }
        DO(0) DO(1) DO(2) DO(3) DO(4) DO(5) DO(6) DO(7)
#undef DO

        float ai = ai0 + ai1;
        float af = af0 + af1;
        float ag = ag0 + ag1;
        float ao = ao0 + ao1;

        // Sum the 4 k-quarter partials inside the wave (lanes 4j..4j+3).
        ai += __shfl_xor(ai, 1); ai += __shfl_xor(ai, 2);
        af += __shfl_xor(af, 1); af += __shfl_xor(af, 2);
        ag += __shfl_xor(ag, 1); ag += __shfl_xor(ag, 2);
        ao += __shfl_xor(ao, 1); ao += __shfl_xor(ao, 2);

        // All 4 lanes compute identically (keeps c replicated, no divergence).
        const float ig  = sigf(ai);
        const float fg  = sigf(af);
        const float gg2 = tanhf_fast(ag);
        const float og  = sigf(ao);
        c = fmaf(fg, c, ig * gg2);
        const float hn = og * tanhf_fast(c);
        if (lead) ((float*)h_il)[widx] = hn;   // 16 lanes/wave, 2-way max (free)
        __syncthreads();                        // the only barrier per step
    }

    // Final linear: out = dot(W_lin, h_T) + b_lin (wave 0).
    if (t < 64) {
        const float* hf = (const float*)h_il;
        const int i0 = ((t >> 2) & 7) * 16 + (t >> 5) * 4 + (t & 3);
        const int t2 = t + 64;
        const int i1 = ((t2 >> 2) & 7) * 16 + (t2 >> 5) * 4 + (t2 & 3);
        float v = Wlin[t] * hf[i0] + Wlin[t2] * hf[i1];
        #pragma unroll
        for (int off = 32; off >= 1; off >>= 1) v += __shfl_down(v, off);
        if (t == 0) out[0] = v + blin[0];
    }
}

extern "C" void kernel_launch(void* const* d_in, const int* in_sizes, int n_in,
                              void* d_out, int out_size, void* d_ws, size_t ws_size,
                              hipStream_t stream) {
    const float* x    = (const float*)d_in[0];
    const float* Wih  = (const float*)d_in[1];
    const float* Whh  = (const float*)d_in[2];
    const float* bih  = (const float*)d_in[3];
    const float* bhh  = (const float*)d_in[4];
    const float* Wlin = (const float*)d_in[5];
    const float* blin = (const float*)d_in[6];
    const float* h0   = (const float*)d_in[7];
    const float* c0   = (const float*)d_in[8];
    float* out = (float*)d_out;
    const int T = in_sizes[0];

    lstm_seq_kernel<<<1, 512, 0, stream>>>(x, Wih, Whh, bih, bhh, Wlin, blin,
                                           h0, c0, out, T);
}

// Round 7
// 5045.341 us; speedup vs baseline: 1.3107x; 1.3107x over previous
//
#include <hip/hip_runtime.h>

#define TMAX 8192
#define H 128

// rcp-based activations: v_rcp_f32 (~1 ulp) instead of the ~12-inst exact-div
// sequence. tanh(x) = 2*sigmoid(2x) - 1.
__device__ __forceinline__ float sigf(float x) {
    return __builtin_amdgcn_rcpf(1.f + __expf(-x));
}
__device__ __forceinline__ float tanhf_fast(float x) {
    return fmaf(2.f, __builtin_amdgcn_rcpf(1.f + __expf(-2.f * x)), -1.f);
}

// Quad butterfly sum via DPP quad_perm (VALU pipe; replaces ds_bpermute shfl).
__device__ __forceinline__ float qsum4(float v) {
    int s = __builtin_amdgcn_update_dpp(0, __float_as_int(v), 0xB1, 0xF, 0xF, true); // [1,0,3,2] xor1
    v += __int_as_float(s);
    s = __builtin_amdgcn_update_dpp(0, __float_as_int(v), 0x4E, 0xF, 0xF, true);     // [2,3,0,1] xor2
    v += __int_as_float(s);
    return v;
}

// One block, 512 threads = 8 waves (2/SIMD).
// Thread t: h-element j = t>>2, k-quarter q = t&3; all 4 gate rows x 32-wide slice.
//
// ROUND 7 (round 6 made compilable): tied "+v" asm constraints are illegal on
// float4 (128-bit) but legal on scalar floats — so the 128 weight floats are
// named SCALARS, pinned per-iteration with zero-instruction asm ties. Parking
// them in AGPR/scratch would now cost a per-iteration copy, so the RA keeps
// them arch-VGPR-resident (budget 256 from waves_per_eu(2,2)).
// Plus: v_rcp_f32 activations (was 5 exact fp32 divisions ~ 50 inst/step) and
// DPP quad-reduce (was 8 ds_bpermute + 2 serial DS latencies).
__attribute__((amdgpu_waves_per_eu(2, 2)))
__global__ __launch_bounds__(512)
void lstm_seq_kernel(const float* __restrict__ x,
                     const float* __restrict__ Wih,
                     const float* __restrict__ Whh,
                     const float* __restrict__ bih,
                     const float* __restrict__ bhh,
                     const float* __restrict__ Wlin,
                     const float* __restrict__ blin,
                     const float* __restrict__ h0,
                     const float* __restrict__ c0,
                     float* __restrict__ out,
                     int T)
{
    __shared__ float  x_s[TMAX];      // 32 KB
    __shared__ float4 h_il[H / 4];    // interleaved h: slot i*4+q = h[q*32 + i*4 .. +3]

    const int t = threadIdx.x;        // 0..511
    const int j = t >> 2;             // h element 0..127
    const int q = t & 3;              // k-quarter

    for (int idx = t; idx < T; idx += 512) x_s[idx] = x[idx];

    const float4* pi = (const float4*)(Whh + (j      ) * H + q * 32);
    const float4* pf = (const float4*)(Whh + (j + 128) * H + q * 32);
    const float4* pg = (const float4*)(Whh + (j + 256) * H + q * 32);
    const float4* po = (const float4*)(Whh + (j + 384) * H + q * 32);

    // One-shot weight loads (asm volatile: issued exactly once, not remat-able).
#define ASMLD4(dst, base, n) \
    { const float4* _a = (base) + (n); \
      asm volatile("global_load_dwordx4 %0, %1, off" : "=v"(dst) : "v"(_a)); }
    float4 wi0, wi1, wi2, wi3, wi4, wi5, wi6, wi7;
    float4 wf0, wf1, wf2, wf3, wf4, wf5, wf6, wf7;
    float4 wg0, wg1, wg2, wg3, wg4, wg5, wg6, wg7;
    float4 wo0, wo1, wo2, wo3, wo4, wo5, wo6, wo7;
#define LOADW(n) \
    ASMLD4(wi##n, pi, n) ASMLD4(wf##n, pf, n) ASMLD4(wg##n, pg, n) ASMLD4(wo##n, po, n)
    LOADW(0) LOADW(1) LOADW(2) LOADW(3) LOADW(4) LOADW(5) LOADW(6) LOADW(7)
#undef LOADW
#undef ASMLD4

#define ASMLD1(dst, ptr) \
    { const float* _a = (ptr); \
      asm volatile("global_load_dword %0, %1, off" : "=v"(dst) : "v"(_a)); }
    float wxi, wxf, wxg, wxo, vbi, vbf, vbg, vbo, vb2i, vb2f, vb2g, vb2o;
    ASMLD1(wxi, Wih + j)        ASMLD1(wxf, Wih + j + 128)
    ASMLD1(wxg, Wih + j + 256)  ASMLD1(wxo, Wih + j + 384)
    ASMLD1(vbi, bih + j)        ASMLD1(vbf, bih + j + 128)
    ASMLD1(vbg, bih + j + 256)  ASMLD1(vbo, bih + j + 384)
    ASMLD1(vb2i, bhh + j)       ASMLD1(vb2f, bhh + j + 128)
    ASMLD1(vb2g, bhh + j + 256) ASMLD1(vb2o, bhh + j + 384)
#undef ASMLD1

    asm volatile("s_waitcnt vmcnt(0)");
    __builtin_amdgcn_sched_barrier(0);   // rule #18: nothing hoists above the wait

    // Decompose to 128 named scalars (pin targets; 32-bit "+v" ties are legal).
#define SPLIT(G,n) \
    float W##G##n##x = w##G##n.x, W##G##n##y = w##G##n.y, \
          W##G##n##z = w##G##n.z, W##G##n##w = w##G##n.w;
    SPLIT(i,0) SPLIT(i,1) SPLIT(i,2) SPLIT(i,3) SPLIT(i,4) SPLIT(i,5) SPLIT(i,6) SPLIT(i,7)
    SPLIT(f,0) SPLIT(f,1) SPLIT(f,2) SPLIT(f,3) SPLIT(f,4) SPLIT(f,5) SPLIT(f,6) SPLIT(f,7)
    SPLIT(g,0) SPLIT(g,1) SPLIT(g,2) SPLIT(g,3) SPLIT(g,4) SPLIT(g,5) SPLIT(g,6) SPLIT(g,7)
    SPLIT(o,0) SPLIT(o,1) SPLIT(o,2) SPLIT(o,3) SPLIT(o,4) SPLIT(o,5) SPLIT(o,6) SPLIT(o,7)
#undef SPLIT

    const bool lead = (q == 0);
    if (!lead) { wxi = 0.f; wxf = 0.f; wxg = 0.f; wxo = 0.f; }
    float bi_ = lead ? vbi + vb2i : 0.f;
    float bf_ = lead ? vbf + vb2f : 0.f;
    float bg_ = lead ? vbg + vb2g : 0.f;
    float bo_ = lead ? vbo + vb2o : 0.f;

    float c = c0[j];                  // replicated across the 4 lanes of a group

    if (t < H) {
        const int fi = ((t >> 2) & 7) * 16 + (t >> 5) * 4 + (t & 3);
        ((float*)h_il)[fi] = h0[t];
    }
    const int widx = ((j >> 2) & 7) * 16 + (j >> 5) * 4 + (j & 3);
    __syncthreads();

    // Zero-instruction residency pin (scalar 32-bit tie).
#define PIN(v) asm("" : "+v"(v));
#define PINS(G,n) PIN(W##G##n##x) PIN(W##G##n##y) PIN(W##G##n##z) PIN(W##G##n##w)

    for (int step = 0; step < T; ++step) {
        // Force all 128 weights (+x-weights/biases) into arch VGPRs each iter.
        PINS(i,0) PINS(i,1) PINS(i,2) PINS(i,3) PINS(i,4) PINS(i,5) PINS(i,6) PINS(i,7)
        PINS(f,0) PINS(f,1) PINS(f,2) PINS(f,3) PINS(f,4) PINS(f,5) PINS(f,6) PINS(f,7)
        PINS(g,0) PINS(g,1) PINS(g,2) PINS(g,3) PINS(g,4) PINS(g,5) PINS(g,6) PINS(g,7)
        PINS(o,0) PINS(o,1) PINS(o,2) PINS(o,3) PINS(o,4) PINS(o,5) PINS(o,6) PINS(o,7)
        PIN(wxi) PIN(wxf) PIN(wxg) PIN(wxo)
        PIN(bi_) PIN(bf_) PIN(bg_) PIN(bo_)

        const float xv = x_s[step];
        float ai0 = fmaf(xv, wxi, bi_), ai1 = 0.f;
        float af0 = fmaf(xv, wxf, bf_), af1 = 0.f;
        float ag0 = fmaf(xv, wxg, bg_), ag1 = 0.f;
        float ao0 = fmaf(xv, wxo, bo_), ao1 = 0.f;

#define DO(n) { \
        const float4 h4 = h_il[n * 4 + q]; \
        ai0 = fmaf(W##i##n##x, h4.x, ai0); ai1 = fmaf(W##i##n##y, h4.y, ai1); \
        ai0 = fmaf(W##i##n##z, h4.z, ai0); ai1 = fmaf(W##i##n##w, h4.w, ai1); \
        af0 = fmaf(W##f##n##x, h4.x, af0); af1 = fmaf(W##f##n##y, h4.y, af1); \
        af0 = fmaf(W##f##n##z, h4.z, af0); af1 = fmaf(W##f##n##w, h4.w, af1); \
        ag0 = fmaf(W##g##n##x, h4.x, ag0); ag1 = fmaf(W##g##n##y, h4.y, ag1); \
        ag0 = fmaf(W##g##n##z, h4.z, ag0); ag1 = fmaf(W##g##n##w, h4.w, ag1); \
        ao0 = fmaf(W##o##n##x, h4.x, ao0); ao1 = fmaf(W##o##n##y, h4.y, ao1); \
        ao0 = fmaf(W##o##n##z, h4.z, ao0); ao1 = fmaf(W##o##n##w, h4.w, ao1); }
        DO(0) DO(1) DO(2) DO(3) DO(4) DO(5) DO(6) DO(7)
#undef DO

        // Quarter-sum inside each quad via DPP (VALU pipe, no DS waits).
        const float ai = qsum4(ai0 + ai1);
        const float af = qsum4(af0 + af1);
        const float ag = qsum4(ag0 + ag1);
        const float ao = qsum4(ao0 + ao1);

        const float ig  = sigf(ai);
        const float fg  = sigf(af);
        const float gg2 = tanhf_fast(ag);
        const float og  = sigf(ao);
        c = fmaf(fg, c, ig * gg2);
        const float hn = og * tanhf_fast(c);
        if (lead) ((float*)h_il)[widx] = hn;   // 16 lanes/wave, 2-way max (free)
        __syncthreads();                        // the only barrier per step
    }
#undef PINS
#undef PIN

    if (t < 64) {
        const float* hf = (const float*)h_il;
        const int i0 = ((t >> 2) & 7) * 16 + (t >> 5) * 4 + (t & 3);
        const int t2 = t + 64;
        const int i1 = ((t2 >> 2) & 7) * 16 + (t2 >> 5) * 4 + (t2 & 3);
        float v = Wlin[t] * hf[i0] + Wlin[t2] * hf[i1];
        #pragma unroll
        for (int off = 32; off >= 1; off >>= 1) v += __shfl_down(v, off);
        if (t == 0) out[0] = v + blin[0];
    }
}

extern "C" void kernel_launch(void* const* d_in, const int* in_sizes, int n_in,
                              void* d_out, int out_size, void* d_ws, size_t ws_size,
                              hipStream_t stream) {
    const float* x    = (const float*)d_in[0];
    const float* Wih  = (const float*)d_in[1];
    const float* Whh  = (const float*)d_in[2];
    const float* bih  = (const float*)d_in[3];
    const float* bhh  = (const float*)d_in[4];
    const float* Wlin = (const float*)d_in[5];
    const float* blin = (const float*)d_in[6];
    const float* h0   = (const float*)d_in[7];
    const float* c0   = (const float*)d_in[8];
    float* out = (float*)d_out;
    const int T = in_sizes[0];

    lstm_seq_kernel<<<1, 512, 0, stream>>>(x, Wih, Whh, bih, bhh, Wlin, blin,
                                           h0, c0, out, T);
}

// Round 8
// 4674.072 us; speedup vs baseline: 1.4148x; 1.0794x over previous
//
#include <hip/hip_runtime.h>

#define TMAX 8192
#define H 128

typedef float v2f __attribute__((ext_vector_type(2)));

// rcp-based activations (v_rcp_f32, ~1 ulp) — proven +1.5ms in round 7.
__device__ __forceinline__ float sigf(float x) {
    return __builtin_amdgcn_rcpf(1.f + __expf(-x));
}
__device__ __forceinline__ float tanhf_fast(float x) {
    return fmaf(2.f, __builtin_amdgcn_rcpf(1.f + __expf(-2.f * x)), -1.f);
}

// Quad butterfly sum via DPP quad_perm (VALU pipe).
__device__ __forceinline__ float qsum4(float v) {
    int s = __builtin_amdgcn_update_dpp(0, __float_as_int(v), 0xB1, 0xF, 0xF, true); // xor1
    v += __int_as_float(s);
    s = __builtin_amdgcn_update_dpp(0, __float_as_int(v), 0x4E, 0xF, 0xF, true);     // xor2
    v += __int_as_float(s);
    return v;
}

// One block, 512 threads = 8 waves (2/SIMD).
// Thread t: h-element j = t>>2, k-quarter q = t&3; all 4 gate rows x 32-wide slice.
//
// ROUND 8: (a) inner matvec in PACKED fp32 — v2f + __builtin_elementwise_fma
// lowers to v_pk_fma_f32 (CDNA packed dual-FMA): 128 -> 64 matvec instructions
// per wave per step, halving the dominant VALU-issue term. (b) h double-buffered
// in LDS: removes the (previously latent) same-step write/read race at zero
// barrier cost. Pins dropped — round 7 proved non-volatile asm pins get LICM'd.
__attribute__((amdgpu_waves_per_eu(2, 2)))
__global__ __launch_bounds__(512)
void lstm_seq_kernel(const float* __restrict__ x,
                     const float* __restrict__ Wih,
                     const float* __restrict__ Whh,
                     const float* __restrict__ bih,
                     const float* __restrict__ bhh,
                     const float* __restrict__ Wlin,
                     const float* __restrict__ blin,
                     const float* __restrict__ h0,
                     const float* __restrict__ c0,
                     float* __restrict__ out,
                     int T)
{
    __shared__ float  x_s[TMAX];         // 32 KB
    __shared__ float4 h_db[2][H / 4];    // double-buffered interleaved h (1 KB)

    const int t = threadIdx.x;           // 0..511
    const int j = t >> 2;                // h element 0..127
    const int q = t & 3;                 // k-quarter

    for (int idx = t; idx < T; idx += 512) x_s[idx] = x[idx];

    const float4* pi = (const float4*)(Whh + (j      ) * H + q * 32);
    const float4* pf = (const float4*)(Whh + (j + 128) * H + q * 32);
    const float4* pg = (const float4*)(Whh + (j + 256) * H + q * 32);
    const float4* po = (const float4*)(Whh + (j + 384) * H + q * 32);

    // One-shot weight loads (asm volatile: issued exactly once, not remat-able).
#define ASMLD4(dst, base, n) \
    { const float4* _a = (base) + (n); \
      asm volatile("global_load_dwordx4 %0, %1, off" : "=v"(dst) : "v"(_a)); }
    float4 wi0, wi1, wi2, wi3, wi4, wi5, wi6, wi7;
    float4 wf0, wf1, wf2, wf3, wf4, wf5, wf6, wf7;
    float4 wg0, wg1, wg2, wg3, wg4, wg5, wg6, wg7;
    float4 wo0, wo1, wo2, wo3, wo4, wo5, wo6, wo7;
#define LOADW(n) \
    ASMLD4(wi##n, pi, n) ASMLD4(wf##n, pf, n) ASMLD4(wg##n, pg, n) ASMLD4(wo##n, po, n)
    LOADW(0) LOADW(1) LOADW(2) LOADW(3) LOADW(4) LOADW(5) LOADW(6) LOADW(7)
#undef LOADW
#undef ASMLD4

#define ASMLD1(dst, ptr) \
    { const float* _a = (ptr); \
      asm volatile("global_load_dword %0, %1, off" : "=v"(dst) : "v"(_a)); }
    float wxi, wxf, wxg, wxo, vbi, vbf, vbg, vbo, vb2i, vb2f, vb2g, vb2o;
    ASMLD1(wxi, Wih + j)        ASMLD1(wxf, Wih + j + 128)
    ASMLD1(wxg, Wih + j + 256)  ASMLD1(wxo, Wih + j + 384)
    ASMLD1(vbi, bih + j)        ASMLD1(vbf, bih + j + 128)
    ASMLD1(vbg, bih + j + 256)  ASMLD1(vbo, bih + j + 384)
    ASMLD1(vb2i, bhh + j)       ASMLD1(vb2f, bhh + j + 128)
    ASMLD1(vb2g, bhh + j + 256) ASMLD1(vb2o, bhh + j + 384)
#undef ASMLD1

    asm volatile("s_waitcnt vmcnt(0)");
    __builtin_amdgcn_sched_barrier(0);   // rule #18: nothing hoists above the wait

    // Split each weight float4 into two aligned v2f halves for pk_fma.
#define SPLIT(G,n) \
    v2f G##a##n = {w##G##n.x, w##G##n.y}; \
    v2f G##b##n = {w##G##n.z, w##G##n.w};
    SPLIT(i,0) SPLIT(i,1) SPLIT(i,2) SPLIT(i,3) SPLIT(i,4) SPLIT(i,5) SPLIT(i,6) SPLIT(i,7)
    SPLIT(f,0) SPLIT(f,1) SPLIT(f,2) SPLIT(f,3) SPLIT(f,4) SPLIT(f,5) SPLIT(f,6) SPLIT(f,7)
    SPLIT(g,0) SPLIT(g,1) SPLIT(g,2) SPLIT(g,3) SPLIT(g,4) SPLIT(g,5) SPLIT(g,6) SPLIT(g,7)
    SPLIT(o,0) SPLIT(o,1) SPLIT(o,2) SPLIT(o,3) SPLIT(o,4) SPLIT(o,5) SPLIT(o,6) SPLIT(o,7)
#undef SPLIT

    const bool lead = (q == 0);
    if (!lead) { wxi = 0.f; wxf = 0.f; wxg = 0.f; wxo = 0.f; }
    const float bi_ = lead ? vbi + vb2i : 0.f;
    const float bf_ = lead ? vbf + vb2f : 0.f;
    const float bg_ = lead ? vbg + vb2g : 0.f;
    const float bo_ = lead ? vbo + vb2o : 0.f;

    float c = c0[j];                  // replicated across the 4 lanes of a group

    if (t < H) {
        const int fi = ((t >> 2) & 7) * 16 + (t >> 5) * 4 + (t & 3);
        ((float*)h_db[0])[fi] = h0[t];
    }
    const int widx = ((j >> 2) & 7) * 16 + (j >> 5) * 4 + (j & 3);
    __syncthreads();

    for (int step = 0; step < T; ++step) {
        const float4* h_rd = h_db[step & 1];
        float*        h_wr = (float*)h_db[(step & 1) ^ 1];

        const float xv = x_s[step];
        v2f aci = {fmaf(xv, wxi, bi_), 0.f};
        v2f acf = {fmaf(xv, wxf, bf_), 0.f};
        v2f acg = {fmaf(xv, wxg, bg_), 0.f};
        v2f aco = {fmaf(xv, wxo, bo_), 0.f};

#define DO(n) { \
        const float4 h4 = h_rd[n * 4 + q]; \
        const v2f hxy = {h4.x, h4.y}; \
        const v2f hzw = {h4.z, h4.w}; \
        aci = __builtin_elementwise_fma(i##a##n, hxy, aci); \
        acf = __builtin_elementwise_fma(f##a##n, hxy, acf); \
        acg = __builtin_elementwise_fma(g##a##n, hxy, acg); \
        aco = __builtin_elementwise_fma(o##a##n, hxy, aco); \
        aci = __builtin_elementwise_fma(i##b##n, hzw, aci); \
        acf = __builtin_elementwise_fma(f##b##n, hzw, acf); \
        acg = __builtin_elementwise_fma(g##b##n, hzw, acg); \
        aco = __builtin_elementwise_fma(o##b##n, hzw, aco); }
        DO(0) DO(1) DO(2) DO(3) DO(4) DO(5) DO(6) DO(7)
#undef DO

        // Quarter-sum inside each quad via DPP (VALU pipe, no DS waits).
        const float ai = qsum4(aci.x + aci.y);
        const float af = qsum4(acf.x + acf.y);
        const float ag = qsum4(acg.x + acg.y);
        const float ao = qsum4(aco.x + aco.y);

        const float ig  = sigf(ai);
        const float fg  = sigf(af);
        const float gg2 = tanhf_fast(ag);
        const float og  = sigf(ao);
        c = fmaf(fg, c, ig * gg2);
        const float hn = og * tanhf_fast(c);
        if (lead) h_wr[widx] = hn;     // other buffer: no same-step race
        __syncthreads();               // the only barrier per step
    }

    // Final linear: out = dot(W_lin, h_T) + b_lin (wave 0). Final h in h_db[T&1].
    if (t < 64) {
        const float* hf = (const float*)h_db[T & 1];
        const int i0 = ((t >> 2) & 7) * 16 + (t >> 5) * 4 + (t & 3);
        const int t2 = t + 64;
        const int i1 = ((t2 >> 2) & 7) * 16 + (t2 >> 5) * 4 + (t2 & 3);
        float v = Wlin[t] * hf[i0] + Wlin[t2] * hf[i1];
        #pragma unroll
        for (int off = 32; off >= 1; off >>= 1) v += __shfl_down(v, off);
        if (t == 0) out[0] = v + blin[0];
    }
}

extern "C" void kernel_launch(void* const* d_in, const int* in_sizes, int n_in,
                              void* d_out, int out_size, void* d_ws, size_t ws_size,
                              hipStream_t stream) {
    const float* x    = (const float*)d_in[0];
    const float* Wih  = (const float*)d_in[1];
    const float* Whh  = (const float*)d_in[2];
    const float* bih  = (const float*)d_in[3];
    const float* bhh  = (const float*)d_in[4];
    const float* Wlin = (const float*)d_in[5];
    const float* blin = (const float*)d_in[6];
    const float* h0   = (const float*)d_in[7];
    const float* c0   = (const float*)d_in[8];
    float* out = (float*)d_out;
    const int T = in_sizes[0];

    lstm_seq_kernel<<<1, 512, 0, stream>>>(x, Wih, Whh, bih, bhh, Wlin, blin,
                                           h0, c0, out, T);
}